// Round 1
// baseline (121.139 us; speedup 1.0000x reference)
//
#include <hip/hip_runtime.h>
#include <math.h>

#define BB 8
#define SS 2048
#define DD 1024
#define MM 4096
#define dd 256
#define BETA 1.0f
#define NCHUNK 32
#define CS (SS/NCHUNK)      // 64
#define RCHUNK 16
#define RCS (MM/RCHUNK)     // 256

// ws offsets in floats
#define OFF_PART 0                          // B*NCHUNK*D = 262144
#define OFF_Q    (OFF_PART + BB*NCHUNK*DD)  // 262144, size B*d=2048
#define OFF_WV   (OFF_Q + BB*dd)            // size 2048
#define OFF_GATE (OFF_WV + BB*dd)           // size 8
#define OFF_SC   (OFF_GATE + BB)            // size 2*B*M = 65536
#define OFF_PRET (OFF_SC + 2*BB*MM)         // size B*RCHUNK*d = 32768
#define OFF_ROUT (OFF_PRET + BB*RCHUNK*dd)  // size B*D = 8192

// K1: partial column sums of x over S-chunks. grid = B*NCHUNK*(D/256), block=256
__global__ void k1_partial(const float* __restrict__ x, float* __restrict__ ws) {
    int blk = blockIdx.x;
    int dblk  = blk % (DD/256);
    int chunk = (blk / (DD/256)) % NCHUNK;
    int b     = blk / ((DD/256)*NCHUNK);
    int col = dblk*256 + threadIdx.x;
    const float* xp = x + ((size_t)b*SS + (size_t)chunk*CS)*DD + col;
    float acc = 0.f;
    #pragma unroll 4
    for (int s = 0; s < CS; ++s) acc += xp[(size_t)s*DD];
    ws[OFF_PART + (b*NCHUNK + chunk)*DD + col] = acc;
}

// K2: x_summary (mean) in LDS, then query / write_value / gate. grid=(B,3), block=256
__global__ void k2_proj(const float* __restrict__ Wq, const float* __restrict__ bq,
                        const float* __restrict__ Wv, const float* __restrict__ bv,
                        const float* __restrict__ Wg, const float* __restrict__ bg,
                        float* __restrict__ ws) {
    __shared__ float xs[DD];
    __shared__ float red[256];
    int b = blockIdx.x;
    int which = blockIdx.y;
    int t = threadIdx.x;
    for (int k = t; k < DD; k += 256) {
        float acc = 0.f;
        for (int c = 0; c < NCHUNK; ++c) acc += ws[OFF_PART + (b*NCHUNK + c)*DD + k];
        xs[k] = acc * (1.0f/SS);
    }
    __syncthreads();
    if (which < 2) {
        const float* W    = (which==0) ? Wq : Wv;
        const float* bias = (which==0) ? bq : bv;
        float acc = 0.f;
        for (int k = 0; k < DD; ++k) acc += xs[k] * W[k*dd + t];
        acc += bias[t];
        ws[(which==0 ? OFF_Q : OFF_WV) + b*dd + t] = acc;
    } else {
        float acc = 0.f;
        for (int k = t; k < DD; k += 256) acc += xs[k] * Wg[k];
        red[t] = acc; __syncthreads();
        for (int s2 = 128; s2 > 0; s2 >>= 1) {
            if (t < s2) red[t] += red[t + s2];
            __syncthreads();
        }
        if (t == 0) ws[OFF_GATE + b] = 1.f / (1.f + __expf(-(red[0] + bg[0])));
    }
}

// K3: read & write scores, one wave per (which,b,m). grid = 2*B*M/4, block=256 (4 waves)
__global__ void k3_scores(const float* __restrict__ memory, float* __restrict__ ws) {
    int wave = threadIdx.x >> 6;
    int lane = threadIdx.x & 63;
    int task = blockIdx.x*4 + wave;           // < 2*B*M
    int m = task % MM;
    int b = (task / MM) % BB;
    int which = task / (BB*MM);
    const float* row = (which == 0) ? (memory + (size_t)m*dd)
                                    : (memory + ((size_t)b*MM + m)*dd);
    const float4 a  = ((const float4*)row)[lane];
    const float4 qv = ((const float4*)(ws + OFF_Q + b*dd))[lane];
    float p = a.x*qv.x + a.y*qv.y + a.z*qv.z + a.w*qv.w;
    #pragma unroll
    for (int off = 32; off > 0; off >>= 1) p += __shfl_xor(p, off);
    if (lane == 0) ws[OFF_SC + (which*BB + b)*MM + m] = p * BETA;
}

// K4: in-place softmax over M per row. grid = 2*B = 16, block=256
__global__ void k4_softmax(float* __restrict__ ws) {
    __shared__ float red[256];
    int row = blockIdx.x;
    float* p = ws + OFF_SC + (size_t)row*MM;
    int t = threadIdx.x;
    float mx = -INFINITY;
    for (int i = t; i < MM; i += 256) mx = fmaxf(mx, p[i]);
    red[t] = mx; __syncthreads();
    for (int s2 = 128; s2 > 0; s2 >>= 1) {
        if (t < s2) red[t] = fmaxf(red[t], red[t + s2]);
        __syncthreads();
    }
    mx = red[0]; __syncthreads();
    float sum = 0.f;
    for (int i = t; i < MM; i += 256) { float e = __expf(p[i] - mx); p[i] = e; sum += e; }
    red[t] = sum; __syncthreads();
    for (int s2 = 128; s2 > 0; s2 >>= 1) {
        if (t < s2) red[t] += red[t + s2];
        __syncthreads();
    }
    float inv = 1.f / red[0];
    for (int i = t; i < MM; i += 256) p[i] *= inv;
}

// K5: partial retrieved = read_attn-chunk @ patterns. grid = B*RCHUNK, block=256
__global__ void k5_pret(const float* __restrict__ memory, float* __restrict__ ws) {
    int blk = blockIdx.x;
    int chunk = blk % RCHUNK;
    int b = blk / RCHUNK;
    int j = threadIdx.x;
    const float* attn = ws + OFF_SC + (size_t)b*MM;   // read_attn rows (which=0)
    float acc = 0.f;
    for (int m = chunk*RCS; m < (chunk+1)*RCS; ++m)
        acc += attn[m] * memory[(size_t)m*dd + j];
    ws[OFF_PRET + (b*RCHUNK + chunk)*dd + j] = acc;
}

// K6: reduce retrieved + read_out = retrieved @ Wo + bo. grid=(B,4), block=256
__global__ void k6_rout(const float* __restrict__ Wo, const float* __restrict__ bo,
                        float* __restrict__ ws) {
    __shared__ float ret[dd];
    int b = blockIdx.x, cb = blockIdx.y, t = threadIdx.x;
    float acc = 0.f;
    for (int c = 0; c < RCHUNK; ++c) acc += ws[OFF_PRET + (b*RCHUNK + c)*dd + t];
    ret[t] = acc; __syncthreads();
    int col = cb*256 + t;
    float o = bo[col];
    for (int j = 0; j < dd; ++j) o += ret[j] * Wo[j*DD + col];
    ws[OFF_ROUT + b*DD + col] = o;
}

// K7: x_augmented = x + read_out broadcast. float4 grid-stride.
__global__ void k7_aug(const float* __restrict__ x, const float* __restrict__ ws,
                       float* __restrict__ out) {
    const float4* x4 = (const float4*)x;
    const float4* r4 = (const float4*)(ws + OFF_ROUT);
    float4* o4 = (float4*)out;
    const int total = BB*SS*DD/4;          // 4194304
    for (int i = blockIdx.x*blockDim.x + threadIdx.x; i < total; i += gridDim.x*blockDim.x) {
        int b = i / (SS*DD/4);
        int c = i % (DD/4);
        float4 xv = x4[i];
        float4 rv = r4[b*(DD/4) + c];
        o4[i] = make_float4(xv.x+rv.x, xv.y+rv.y, xv.z+rv.z, xv.w+rv.w);
    }
}

// K8: memory_new = 0.95*memory + 0.05*w_attn*gate*write_value. float4 grid-stride.
__global__ void k8_mem(const float* __restrict__ memory, const float* __restrict__ ws,
                       float* __restrict__ out) {
    const float4* m4 = (const float4*)memory;
    float4* o4 = (float4*)(out + (size_t)BB*SS*DD);
    const int total = BB*MM*dd/4;          // 2097152
    for (int i = blockIdx.x*blockDim.x + threadIdx.x; i < total; i += gridDim.x*blockDim.x) {
        int b  = i / (MM*dd/4);
        int m  = (i / (dd/4)) % MM;
        int d4 = i % (dd/4);
        float coeff = 0.05f * ws[OFF_SC + (BB + b)*MM + m] * ws[OFF_GATE + b];
        float4 wv = ((const float4*)(ws + OFF_WV))[b*(dd/4) + d4];
        float4 mv = m4[i];
        o4[i] = make_float4(0.95f*mv.x + coeff*wv.x,
                            0.95f*mv.y + coeff*wv.y,
                            0.95f*mv.z + coeff*wv.z,
                            0.95f*mv.w + coeff*wv.w);
    }
}

extern "C" void kernel_launch(void* const* d_in, const int* in_sizes, int n_in,
                              void* d_out, int out_size, void* d_ws, size_t ws_size,
                              hipStream_t stream) {
    const float* x      = (const float*)d_in[0];
    const float* memory = (const float*)d_in[1];
    const float* Wq     = (const float*)d_in[2];
    const float* bq     = (const float*)d_in[3];
    const float* Wv     = (const float*)d_in[4];
    const float* bv     = (const float*)d_in[5];
    const float* Wo     = (const float*)d_in[6];
    const float* bo     = (const float*)d_in[7];
    const float* Wg     = (const float*)d_in[8];
    const float* bg     = (const float*)d_in[9];
    float* out = (float*)d_out;
    float* ws  = (float*)d_ws;

    k1_partial<<<BB*NCHUNK*(DD/256), 256, 0, stream>>>(x, ws);
    k2_proj<<<dim3(BB,3), 256, 0, stream>>>(Wq, bq, Wv, bv, Wg, bg, ws);
    k3_scores<<<2*BB*MM/4, 256, 0, stream>>>(memory, ws);
    k4_softmax<<<2*BB, 256, 0, stream>>>(ws);
    k5_pret<<<BB*RCHUNK, 256, 0, stream>>>(memory, ws);
    k6_rout<<<dim3(BB,4), 256, 0, stream>>>(Wo, bo, ws);
    k7_aug<<<2048, 256, 0, stream>>>(x, ws, out);
    k8_mem<<<1024, 256, 0, stream>>>(memory, ws, out);
}